// Round 20
// baseline (40.986 us; speedup 1.0000x reference)
//
#include <hip/hip_runtime.h>

#define NTEST  16384
#define NTRAIN 8192
#define DIM    64
#define NCOLSPLIT 16
#define WPB    8                            // waves per block (512 threads)

typedef _Float16 f16x8  __attribute__((ext_vector_type(8)));
typedef float    f32x16 __attribute__((ext_vector_type(16)));

#define LOG2E 1.4426950408889634f

// Direct global->LDS DMA: no staging VGPRs, linear wave-contiguous LDS writes.
#define GLOAD_LDS16(gsrc, ldst)                                                     \
    __builtin_amdgcn_global_load_lds(                                               \
        (const __attribute__((address_space(1))) unsigned int*)(gsrc),              \
        (__attribute__((address_space(3))) unsigned int*)(ldst), 16, 0, 0)

// Rows [0,NTEST) = test_X -> A_hi = f16(x * s1) (PRE-SCALED by inv2*log2e so
// the MFMA emits the exp argument's dot term directly) + nx2 = cn*nx
// (+ zeroes out[row]). Rows [NTEST,..) = train_X -> B_hi = f16(x) UNSCALED
// (only one operand side may carry the scale) in TILE-MAJOR layout +
// wt = alpha * exp2(cn*nt).
// Tile-major: for train row r, dim k:
//   flat = (r>>5)*2048 + (k>>4)*512 + (((k>>3)&1)*32 + (r&31))*8 + (k&7)
__global__ __launch_bounds__(256) void krr_prep(
    const float* __restrict__ test_X, const float* __restrict__ train_X,
    const float* __restrict__ alphas, const float* __restrict__ lengthscale,
    _Float16* __restrict__ A_hi, _Float16* __restrict__ B_hi,
    float* __restrict__ nx2, float* __restrict__ wt, float* __restrict__ out)
{
    int gwave = (blockIdx.x * 256 + threadIdx.x) >> 6;
    int lane  = threadIdx.x & 63;           // = dim index k
    bool is_test = gwave < NTEST;
    int row = is_test ? gwave : gwave - NTEST;
    const float* src = is_test ? test_X : train_X;

    float ls   = lengthscale[0];
    float inv2 = 1.0f / (ls * ls);
    float s1   = inv2 * LOG2E;               // dot coefficient (log2 domain)
    float cn   = -0.5f * inv2 * LOG2E;       // norm coefficient (log2 domain)

    float x = src[(size_t)row * DIM + lane];

    if (is_test) {
        A_hi[(size_t)row * DIM + lane] = (_Float16)(x * s1);  // pre-scaled
    } else {
        _Float16 h = (_Float16)x;                             // unscaled
        int t  = row >> 5, lr = row & 31;
        int kk = lane >> 4, hi = (lane >> 3) & 1, e = lane & 7;
        size_t dst = (size_t)t * 2048 + (size_t)kk * 512 + (size_t)(hi * 32 + lr) * 8 + e;
        B_hi[dst] = h;
    }

    float s = x * x;
    s += __shfl_xor(s, 1);  s += __shfl_xor(s, 2);  s += __shfl_xor(s, 4);
    s += __shfl_xor(s, 8);  s += __shfl_xor(s, 16); s += __shfl_xor(s, 32);
    if (lane == 0) {
        if (is_test) { nx2[row] = s * cn; out[row] = 0.0f; }
        else         wt[row]  = alphas[row] * __builtin_amdgcn_exp2f(cn * s);
    }
}

// r19 structure + LOCKSTEP BREAKING. Diagnosis: serial pipe-time sum (LDS
// 10.3 + VALU/trans 8.5 + MFMA 6.9 us) == measured 28 us — co-resident
// waves run the identical post-barrier instruction sequence, phase-lock,
// and serialize the pipes (all-MFMA, then all-trans). Fix: (1) wave-uniform
// s_sleep stagger after each barrier (waves sharing a SIMD offset by ~640
// cyc ~ half a pair-iter, cost <=0.4us); (2) T5 setprio(1) around MFMA
// clusters — pays only with wave role diversity, which the stagger creates.
// Math/registers identical to r19. K*alpha = exp2(C[r]) * wt[col].
__global__ __launch_bounds__(512) void krr_mfma(
    const _Float16* __restrict__ A_hi, const _Float16* __restrict__ B_hi,
    const float* __restrict__ nx2, const float* __restrict__ wt,
    const float* __restrict__ lengthscale, float* __restrict__ out)
{
    alignas(16) __shared__ _Float16 BsA[8 * 2048];  // 32 KB (phase 0)
    alignas(16) __shared__ _Float16 BsB[8 * 2048];  // 32 KB (phase 1)
    __shared__ float wts[512];                      // 2 KB

    const int tid   = threadIdx.x;
    const int lane  = tid & 63;
    const int wave  = tid >> 6;
    const int rbase = blockIdx.x * 256 + wave * 32;
    const int cb    = blockIdx.y;                   // col-split index

    // Desync co-resident waves. s_sleep imm = units of 64 cyc (imm-only, so
    // a wave-uniform scalar switch). Assuming wave->SIMD = wave&3, the two
    // waves of this WG on one SIMD ({w, w+4}) are offset by 10 units = 640
    // cyc ~ half a pair-iter.
    #define STAGGER()                                                           \
        switch (wave) {                                                         \
            case 1: __builtin_amdgcn_s_sleep(2);  break;                        \
            case 2: __builtin_amdgcn_s_sleep(4);  break;                        \
            case 3: __builtin_amdgcn_s_sleep(6);  break;                        \
            case 4: __builtin_amdgcn_s_sleep(10); break;                        \
            case 5: __builtin_amdgcn_s_sleep(12); break;                        \
            case 6: __builtin_amdgcn_s_sleep(14); break;                        \
            case 7: __builtin_amdgcn_s_sleep(16); break;                        \
            default: break;                                                     \
        }

    // Wave w DMAs tile (p*8 + w) of the strip: 4 x 1KB global_load_lds.
    #define STAGE8(p, buf)                                                      \
        {                                                                       \
            const _Float16* gt = B_hi + ((size_t)cb * 16 + (p) * 8 + wave) * 2048 \
                               + (size_t)lane * 8;                              \
            _Float16* lt0 = (buf) + (size_t)wave * 2048;                        \
            GLOAD_LDS16(gt,        lt0);                                        \
            GLOAD_LDS16(gt + 512,  lt0 + 512);                                  \
            GLOAD_LDS16(gt + 1024, lt0 + 1024);                                 \
            GLOAD_LDS16(gt + 1536, lt0 + 1536);                                 \
        }

    // Compute 8 tiles of phase p: pair-rotated (r18), chains seeded with
    // nxcv via the first MFMA's C operand (r19); epilogue = exp2 + fma.
    // setprio(1) keeps MFMA-entering waves favored by the CU scheduler.
    #define COMPUTE8(p, buf)                                                    \
        {                                                                       \
            const _Float16* pbase = (buf) + (size_t)lane * 8;                   \
            f16x8 bhA[4], bhB[4];                                               \
            _Pragma("unroll")                                                   \
            for (int kk = 0; kk < 4; ++kk) {                                    \
                bhA[kk] = *reinterpret_cast<const f16x8*>(pbase + kk * 512);    \
                bhB[kk] = *reinterpret_cast<const f16x8*>(pbase + 2048 + kk * 512); \
            }                                                                   \
            _Pragma("unroll 1")                                                 \
            for (int lt = 0; lt < 8; lt += 2) {                                 \
                __builtin_amdgcn_s_setprio(1);                                  \
                f32x16 CA = __builtin_amdgcn_mfma_f32_32x32x16_f16(ah[0], bhA[0], nxcv, 0, 0, 0); \
                f32x16 CB = __builtin_amdgcn_mfma_f32_32x32x16_f16(ah[0], bhB[0], nxcv, 0, 0, 0); \
                _Pragma("unroll")                                               \
                for (int kk = 1; kk < 4; ++kk) {                                \
                    CA = __builtin_amdgcn_mfma_f32_32x32x16_f16(ah[kk], bhA[kk], CA, 0, 0, 0); \
                    CB = __builtin_amdgcn_mfma_f32_32x32x16_f16(ah[kk], bhB[kk], CB, 0, 0, 0); \
                }                                                               \
                __builtin_amdgcn_s_setprio(0);                                  \
                const int wtb = ((p) * 8 + lt) * 32 + (lane & 31);              \
                const float wA = wts[wtb];                                      \
                const float wB = wts[wtb + 32];                                 \
                if (lt < 6) {                                                   \
                    const _Float16* pn = pbase + (size_t)(lt + 2) * 2048;       \
                    _Pragma("unroll")                                           \
                    for (int kk = 0; kk < 4; ++kk) {                            \
                        bhA[kk] = *reinterpret_cast<const f16x8*>(pn + kk * 512); \
                        bhB[kk] = *reinterpret_cast<const f16x8*>(pn + 2048 + kk * 512); \
                    }                                                           \
                }                                                               \
                _Pragma("unroll")                                               \
                for (int r = 0; r < 16; ++r) {                                  \
                    acc[r] = fmaf(__builtin_amdgcn_exp2f(CA[r]), wA, acc[r]);   \
                    acc[r] = fmaf(__builtin_amdgcn_exp2f(CB[r]), wB, acc[r]);   \
                }                                                               \
            }                                                                   \
        }

    // Issue phase-0 stage + weights immediately.
    STAGE8(0, BsA);
    wts[tid] = wt[cb * 512 + tid];

    const int arow = rbase + (lane & 31);
    const int koff = (lane >> 5) * 8;        // canonical k-map, same for A and B

    // A fragments (pre-scaled by s1), loop-invariant: 4 x 16B = 16 VGPRs
    f16x8 ah[4];
    #pragma unroll
    for (int kk = 0; kk < 4; ++kk)
        ah[kk] = *reinterpret_cast<const f16x8*>(A_hi + (size_t)arow * DIM + kk * 16 + koff);

    // C-seed: cn*nx for the 16 C/D rows this lane holds (consumed by the
    // first MFMA of every chain as its C operand).
    f32x16 nxcv;
    #pragma unroll
    for (int r = 0; r < 16; ++r) {
        int row = (r & 3) + 8 * (r >> 2) + 4 * (lane >> 5);
        nxcv[r] = nx2[rbase + row];
    }

    float acc[16];
    #pragma unroll
    for (int r = 0; r < 16; ++r) acc[r] = 0.0f;

    __syncthreads();              // BsA ready (the one exposed stage wait)
    STAGGER();                    // desync before the long compute phase

    STAGE8(1, BsB);               // issued now; latency hidden under COMPUTE8(0)
    COMPUTE8(0, BsA);

    __syncthreads();              // drains BsB loads (covered by compute above)
    STAGGER();                    // barrier re-synced the waves; desync again

    COMPUTE8(1, BsB);

    #undef STAGE8
    #undef COMPUTE8
    #undef STAGGER

    // Sum over the 32 train cols held across lanes of the same half.
    #pragma unroll
    for (int r = 0; r < 16; ++r) {
        float v = acc[r];
        v += __shfl_xor(v, 1);  v += __shfl_xor(v, 2);  v += __shfl_xor(v, 4);
        v += __shfl_xor(v, 8);  v += __shfl_xor(v, 16);
        if ((lane & 31) == 0) {
            int row = (r & 3) + 8 * (r >> 2) + 4 * (lane >> 5);
            atomicAdd(&out[rbase + row], v);
        }
    }
}

// ---------------- fallback (round-1 kernel, known-good) ----------------
#define TCHUNK 512
#define NCHUNK (NTRAIN / TCHUNK)
__global__ __launch_bounds__(256, 4) void krr_main(
    const float* __restrict__ test_X, const float* __restrict__ train_X,
    const float* __restrict__ alphas, const float* __restrict__ lengthscale,
    float* __restrict__ out)
{
    __shared__ float nt_lds[TCHUNK];
    __shared__ float al_lds[TCHUNK];
    const int tid = threadIdx.x;
    const int i   = blockIdx.x * 256 + tid;
    const int j0  = blockIdx.y * TCHUNK;
    const float ls   = lengthscale[0];
    const float inv2 = 1.0f / (ls * ls);
    for (int jj = tid; jj < TCHUNK; jj += 256) {
        const float4* tr = reinterpret_cast<const float4*>(train_X + (size_t)(j0 + jj) * DIM);
        float s = 0.f;
        #pragma unroll
        for (int k = 0; k < DIM / 4; ++k) {
            float4 t = tr[k];
            s += t.x * t.x + t.y * t.y + t.z * t.z + t.w * t.w;
        }
        nt_lds[jj] = s * inv2;
        al_lds[jj] = alphas[j0 + jj];
    }
    __syncthreads();
    float xr[DIM]; float nxv = 0.f;
    {
        const float4* xp = reinterpret_cast<const float4*>(test_X + (size_t)i * DIM);
        #pragma unroll
        for (int k = 0; k < DIM / 4; ++k) {
            float4 v = xp[k];
            xr[4*k+0] = v.x; xr[4*k+1] = v.y; xr[4*k+2] = v.z; xr[4*k+3] = v.w;
            nxv += v.x*v.x + v.y*v.y + v.z*v.z + v.w*v.w;
        }
        nxv *= inv2;
        #pragma unroll
        for (int k = 0; k < DIM; ++k) xr[k] *= inv2;
    }
    float acc = 0.f;
    for (int jj = 0; jj < TCHUNK; ++jj) {
        const float* trow = train_X + (size_t)(j0 + jj) * DIM;
        float d0 = 0.f, d1 = 0.f, d2 = 0.f, d3 = 0.f;
        #pragma unroll
        for (int k4 = 0; k4 < DIM / 4; ++k4) {
            float4 t = reinterpret_cast<const float4*>(trow)[k4];
            d0 = fmaf(xr[4*k4+0], t.x, d0);
            d1 = fmaf(xr[4*k4+1], t.y, d1);
            d2 = fmaf(xr[4*k4+2], t.z, d2);
            d3 = fmaf(xr[4*k4+3], t.w, d3);
        }
        float dot = (d0 + d1) + (d2 + d3);
        float sq  = nxv + nt_lds[jj] - 2.0f * dot;
        sq = fmaxf(sq, 0.0f);
        acc = fmaf(__expf(-0.5f * sq), al_lds[jj], acc);
    }
    atomicAdd(&out[i], acc);
}

extern "C" void kernel_launch(void* const* d_in, const int* in_sizes, int n_in,
                              void* d_out, int out_size, void* d_ws, size_t ws_size,
                              hipStream_t stream) {
    const float* test_X      = (const float*)d_in[0];
    const float* train_X     = (const float*)d_in[1];
    const float* alphas      = (const float*)d_in[2];
    const float* lengthscale = (const float*)d_in[3];
    float* out = (float*)d_out;

    const size_t need = (size_t)(NTEST + NTRAIN) * DIM * sizeof(_Float16)
                      + (NTEST + NTRAIN) * sizeof(float);
    if (ws_size >= need) {
        _Float16* A_hi = (_Float16*)d_ws;
        _Float16* B_hi = A_hi + (size_t)NTEST * DIM;
        float*    nx2  = (float*)(B_hi + (size_t)NTRAIN * DIM);
        float*    wtp  = nx2 + NTEST;

        // prep also zeroes `out` (memset launch folded in).
        krr_prep<<<(NTEST + NTRAIN) / 4, 256, 0, stream>>>(
            test_X, train_X, alphas, lengthscale, A_hi, B_hi, nx2, wtp, out);

        dim3 grid(NTEST / 256, NCOLSPLIT);
        krr_mfma<<<grid, 64 * WPB, 0, stream>>>(A_hi, B_hi, nx2, wtp,
                                                lengthscale, out);
    } else {
        hipMemsetAsync(out, 0, NTEST * sizeof(float), stream);
        dim3 grid(NTEST / 256, NCHUNK);
        krr_main<<<grid, 256, 0, stream>>>(test_X, train_X, alphas, lengthscale, out);
    }
}